// Round 2
// baseline (577.121 us; speedup 1.0000x reference)
//
#include <hip/hip_runtime.h>
#include <hip/hip_bf16.h>

// GraphSAGE 3-layer inference, MI355X — fused gather+GEMM version.
//
// Key identity: A-tile columns are either "self" (k < D, from X[row]) or
// "neighbor mean" (k >= D, mean of F rows of X). Staging does the gather +
// mean + f32->bf16 convert directly into LDS; no materialized concat buffer.
//
// Pipeline (5 launches):
//   prep_wcat x2 : Wt[n][k] = bf16([Wself;Wneigh]^T)
//   sage_gemm<1024,10> : h0 = relu([x_self|mean nbr0] @ Wt0^T + b0)  (25600x256 f32)
//   sage_gemm<256,10>  : h1 = relu([h0_self|mean nbr1] @ Wt1^T + b1) (2560x256 f32)
//   out_fused          : out = [h1_self|mean nbr2] @ [Ws2;Wn2] + b2  (512x19 f32)

typedef __attribute__((ext_vector_type(4))) float f32x4;
typedef __attribute__((ext_vector_type(8))) short s16x8;

__device__ __forceinline__ unsigned short f2bf_u16(float f) {
  // round-to-nearest-even f32 -> bf16 (finite inputs only)
  unsigned int u = __float_as_uint(f);
  u += 0x7fffu + ((u >> 16) & 1u);
  return (unsigned short)(u >> 16);
}

__device__ __forceinline__ s16x8 pack_bf16x8(const float4& a, const float4& b) {
  s16x8 w;
  w[0] = (short)f2bf_u16(a.x); w[1] = (short)f2bf_u16(a.y);
  w[2] = (short)f2bf_u16(a.z); w[3] = (short)f2bf_u16(a.w);
  w[4] = (short)f2bf_u16(b.x); w[5] = (short)f2bf_u16(b.y);
  w[6] = (short)f2bf_u16(b.z); w[7] = (short)f2bf_u16(b.w);
  return w;
}

// Wt[n][k] = bf16( k<Khalf ? Wself[k][n] : Wneigh[k-Khalf][n] )
__global__ void prep_wcat(const float* __restrict__ Wself,
                          const float* __restrict__ Wneigh,
                          unsigned short* __restrict__ Wt, int Khalf, int N) {
  int idx = blockIdx.x * 256 + threadIdx.x;
  int Kc = 2 * Khalf;
  if (idx >= N * Kc) return;
  int n = idx / Kc, k = idx - n * Kc;
  float v = (k < Khalf) ? Wself[(size_t)k * N + n] : Wneigh[(size_t)(k - Khalf) * N + n];
  Wt[idx] = f2bf_u16(v);
}

// Fused gather + mean + GEMM. Fixed geometry: BM=64, BN=N=256, BK=64,
// 256 threads (4 waves, each owning a 64x64 output quadrant of the N dim).
// C[m][n] = act( sum_k Acat[m][k] * Bt[n][k] + bias[n] )
//   Acat[m][k] = k<D ? X[bm+m][k] : mean_f X[nbr[bm+m][f]][k-D]   (bf16-rounded)
// MFMA 16x16x32_bf16; A/B frag: row=lane&15, k=8*(lane>>4)+j;
// C/D frag: col=lane&15, row=(lane>>4)*4+r.
template <int D, int F, bool RELU>
__global__ void sage_gemm(const float* __restrict__ X,
                          const int* __restrict__ nbr,
                          const unsigned short* __restrict__ Bt,
                          const float* __restrict__ bias,
                          float* __restrict__ C) {
  constexpr int BM = 64, BN = 256, BK = 64;
  constexpr int LDK = BK + 8;  // 144B row stride -> <=2-way LDS bank aliasing (free)
  constexpr int Kc = 2 * D;
  __shared__ __align__(16) unsigned short As[BM][LDK];
  __shared__ __align__(16) unsigned short Bs[BN][LDK];

  const int tid = threadIdx.x;
  const int wid = tid >> 6, lane = tid & 63;
  const size_t bm = (size_t)blockIdx.x * BM;

  // staging assignment: 4 threads per row, 16 floats (4x float4) each
  const int r = tid >> 2;
  const int coff = (tid & 3) * 16;

  int idx[F];
#pragma unroll
  for (int f = 0; f < F; ++f) idx[f] = nbr[(bm + r) * F + f];

  f32x4 acc[4][4];
#pragma unroll
  for (int mi = 0; mi < 4; ++mi)
#pragma unroll
    for (int ni = 0; ni < 4; ++ni)
      acc[mi][ni] = (f32x4){0.f, 0.f, 0.f, 0.f};

  const int klo = (lane >> 4) * 8;
  const int l15 = lane & 15;

  for (int kt = 0; kt < Kc; kt += BK) {
    // ---- stage A-tile: gather + mean + convert ----
    float4 v0, v1, v2, v3;
    if (kt < D) {
      const float4* p = reinterpret_cast<const float4*>(X + (bm + r) * (size_t)D + kt + coff);
      v0 = p[0]; v1 = p[1]; v2 = p[2]; v3 = p[3];
    } else {
      v0 = v1 = v2 = v3 = make_float4(0.f, 0.f, 0.f, 0.f);
      const int kk = kt - D + coff;
#pragma unroll
      for (int f = 0; f < F; ++f) {
        const float4* p = reinterpret_cast<const float4*>(X + (size_t)idx[f] * D + kk);
        float4 u0 = p[0], u1 = p[1], u2 = p[2], u3 = p[3];
        v0.x += u0.x; v0.y += u0.y; v0.z += u0.z; v0.w += u0.w;
        v1.x += u1.x; v1.y += u1.y; v1.z += u1.z; v1.w += u1.w;
        v2.x += u2.x; v2.y += u2.y; v2.z += u2.z; v2.w += u2.w;
        v3.x += u3.x; v3.y += u3.y; v3.z += u3.z; v3.w += u3.w;
      }
      constexpr float inv = 1.0f / (float)F;
      v0.x *= inv; v0.y *= inv; v0.z *= inv; v0.w *= inv;
      v1.x *= inv; v1.y *= inv; v1.z *= inv; v1.w *= inv;
      v2.x *= inv; v2.y *= inv; v2.z *= inv; v2.w *= inv;
      v3.x *= inv; v3.y *= inv; v3.z *= inv; v3.w *= inv;
    }
    *reinterpret_cast<s16x8*>(&As[r][coff]) = pack_bf16x8(v0, v1);
    *reinterpret_cast<s16x8*>(&As[r][coff + 8]) = pack_bf16x8(v2, v3);

    // ---- stage B-tile: 4 passes of 64 rows, 4 threads/row ----
#pragma unroll
    for (int pz = 0; pz < 4; ++pz) {
      const int row = pz * 64 + r;
      const s16x8* pb = reinterpret_cast<const s16x8*>(Bt + (size_t)row * Kc + kt + coff);
      s16x8 b0 = pb[0], b1 = pb[1];
      *reinterpret_cast<s16x8*>(&Bs[row][coff]) = b0;
      *reinterpret_cast<s16x8*>(&Bs[row][coff + 8]) = b1;
    }
    __syncthreads();

    // ---- MFMA: 2 sub-steps of K=32 ----
#pragma unroll
    for (int ks = 0; ks < 2; ++ks) {
      s16x8 af[4], bfr[4];
#pragma unroll
      for (int mi = 0; mi < 4; ++mi)
        af[mi] = *reinterpret_cast<const s16x8*>(&As[mi * 16 + l15][ks * 32 + klo]);
#pragma unroll
      for (int ni = 0; ni < 4; ++ni)
        bfr[ni] = *reinterpret_cast<const s16x8*>(&Bs[wid * 64 + ni * 16 + l15][ks * 32 + klo]);
#pragma unroll
      for (int mi = 0; mi < 4; ++mi)
#pragma unroll
        for (int ni = 0; ni < 4; ++ni)
          acc[mi][ni] = __builtin_amdgcn_mfma_f32_16x16x32_bf16(af[mi], bfr[ni], acc[mi][ni], 0, 0, 0);
    }
    __syncthreads();
  }

  // ---- epilogue: bias (+relu), f32 store ----
  const int rif = (lane >> 4) * 4;
#pragma unroll
  for (int mi = 0; mi < 4; ++mi) {
    const size_t r0 = bm + mi * 16 + rif;
#pragma unroll
    for (int ni = 0; ni < 4; ++ni) {
      const int c = wid * 64 + ni * 16 + l15;
      const float bv = bias[c];
#pragma unroll
      for (int rr = 0; rr < 4; ++rr) {
        float v = acc[mi][ni][rr] + bv;
        if (RELU) v = fmaxf(v, 0.f);
        C[(r0 + rr) * (size_t)BN + c] = v;
      }
    }
  }
}

// Final layer fused: row = [h1[i] | mean_5 h1[nbr2[i]]], out = row @ [Ws2;Wn2] + b2
__global__ void out_fused(const float* __restrict__ h1, const int* __restrict__ nbr,
                          const float* __restrict__ Ws, const float* __restrict__ Wn,
                          const float* __restrict__ b, float* __restrict__ out) {
  const int i = blockIdx.x, t = threadIdx.x;  // 256 threads
  __shared__ float row[512];
  __shared__ float part[8][32];
  row[t] = h1[(size_t)i * 256 + t];
  float s = 0.f;
#pragma unroll
  for (int f = 0; f < 5; ++f) s += h1[(size_t)nbr[i * 5 + f] * 256 + t];
  row[256 + t] = s * 0.2f;
  __syncthreads();
  const int n = t & 31, seg = t >> 5;  // 8 segments x 64 k-elems
  float p = 0.f;
  if (n < 19) {
#pragma unroll
    for (int e = 0; e < 64; ++e) {
      const int k = seg * 64 + e;
      const float w = (k < 256) ? Ws[k * 19 + n] : Wn[(k - 256) * 19 + n];
      p += row[k] * w;
    }
  }
  part[seg][n] = p;
  __syncthreads();
  if (t < 19) {
    float sm = b[t];
#pragma unroll
    for (int g = 0; g < 8; ++g) sm += part[g][t];
    out[(size_t)i * 19 + t] = sm;
  }
}

extern "C" void kernel_launch(void* const* d_in, const int* in_sizes, int n_in,
                              void* d_out, int out_size, void* d_ws, size_t ws_size,
                              hipStream_t stream) {
  const float* x    = (const float*)d_in[0];
  const int*   nbr0 = (const int*)d_in[1];
  const int*   nbr1 = (const int*)d_in[2];
  const int*   nbr2 = (const int*)d_in[3];
  const float* Ws0  = (const float*)d_in[4];
  const float* Wn0  = (const float*)d_in[5];
  const float* b0   = (const float*)d_in[6];
  const float* Ws1  = (const float*)d_in[7];
  const float* Wn1  = (const float*)d_in[8];
  const float* b1   = (const float*)d_in[9];
  const float* Ws2  = (const float*)d_in[10];
  const float* Wn2  = (const float*)d_in[11];
  const float* b2   = (const float*)d_in[12];
  float* out = (float*)d_out;

  char* ws = (char*)d_ws;
  unsigned short* Wt0 = (unsigned short*)(ws);              // 256*2048*2 = 1048576
  unsigned short* Wt1 = (unsigned short*)(ws + 1048576);    // 256*512*2  =  262144
  float*          h0  = (float*)(ws + 1310720);             // 25600*256*4 = 26214400
  float*          h1  = (float*)(ws + 27525120);            // 2560*256*4  =  2621440
  // total ws use: ~30.1 MB

  prep_wcat<<<(256 * 2048 + 255) / 256, 256, 0, stream>>>(Ws0, Wn0, Wt0, 1024, 256);
  prep_wcat<<<(256 * 512 + 255) / 256, 256, 0, stream>>>(Ws1, Wn1, Wt1, 256, 256);

  sage_gemm<1024, 10, true><<<25600 / 64, 256, 0, stream>>>(x, nbr0, Wt0, b0, h0);
  sage_gemm<256, 10, true><<<2560 / 64, 256, 0, stream>>>(h0, nbr1, Wt1, b1, h1);
  out_fused<<<512, 256, 0, stream>>>(h1, nbr2, Ws2, Wn2, b2, out);
}

// Round 3
// 310.623 us; speedup vs baseline: 1.8580x; 1.8580x over previous
//
#include <hip/hip_runtime.h>
#include <hip/hip_bf16.h>

// GraphSAGE 3-layer inference, MI355X — separated gather + MFMA GEMM (R1
// structure, tuned). R2's fused-gather GEMM regressed 322->577us (6 waves/CU,
// serial latency exposure); reverted. This round: gemm0 occupancy fix
// (200 blocks @512thr -> 400 blocks @256thr) + fused final layer.
//
// Pipeline (7 launches):
//   prep_wcat x2       : Wt[n][k] = bf16([Wself;Wneigh]^T)
//   gather_cat<1024,10>: A0 = [bf16(x_self) | bf16(mean nbr0)]   (25600 x 2048)
//   gemm_bf16          : h0 = relu(A0 @ Wt0^T + b0)              (25600 x 256 f32)
//   gather_cat<256,10> : cat1                                    (2560 x 512)
//   gemm_bf16          : h1 = relu(cat1 @ Wt1^T + b1)            (2560 x 256 f32)
//   out_fused          : out = [h1|mean nbr2] @ [Ws2;Wn2] + b2   (512 x 19 f32)

typedef __attribute__((ext_vector_type(4))) float f32x4;
typedef __attribute__((ext_vector_type(8))) short s16x8;

__device__ __forceinline__ unsigned short f2bf_u16(float f) {
  // round-to-nearest-even f32 -> bf16 (finite inputs only)
  unsigned int u = __float_as_uint(f);
  u += 0x7fffu + ((u >> 16) & 1u);
  return (unsigned short)(u >> 16);
}

__device__ __forceinline__ float bf2f(unsigned short u) {
  return __uint_as_float(((unsigned int)u) << 16);
}

// Wt[n][k] = bf16( k<Khalf ? Wself[k][n] : Wneigh[k-Khalf][n] )
__global__ void prep_wcat(const float* __restrict__ Wself,
                          const float* __restrict__ Wneigh,
                          unsigned short* __restrict__ Wt, int Khalf, int N) {
  int idx = blockIdx.x * 256 + threadIdx.x;
  int Kc = 2 * Khalf;
  if (idx >= N * Kc) return;
  int n = idx / Kc, k = idx - n * Kc;
  float v = (k < Khalf) ? Wself[(size_t)k * N + n] : Wneigh[(size_t)(k - Khalf) * N + n];
  Wt[idx] = f2bf_u16(v);
}

// One block per dst node; blockDim.x == D/4 exactly.
// out row (2*D bf16) = [ self | mean over F sampled neighbors ]
template <int D, int F>
__global__ void gather_cat(const float* __restrict__ h,
                           const int* __restrict__ nbr,
                           unsigned short* __restrict__ out) {
  const int i = blockIdx.x;
  const int c = threadIdx.x;  // float4 slot
  int idx[F];
#pragma unroll
  for (int f = 0; f < F; ++f) idx[f] = nbr[(size_t)i * F + f];
  constexpr float inv = 1.0f / (float)F;

  float4 s = reinterpret_cast<const float4*>(h + (size_t)i * D)[c];
  ushort4 us = {f2bf_u16(s.x), f2bf_u16(s.y), f2bf_u16(s.z), f2bf_u16(s.w)};
  reinterpret_cast<ushort4*>(out + (size_t)i * 2 * D)[c] = us;

  float ax = 0.f, ay = 0.f, az = 0.f, aw = 0.f;
#pragma unroll
  for (int f = 0; f < F; ++f) {
    float4 v = reinterpret_cast<const float4*>(h + (size_t)idx[f] * D)[c];
    ax += v.x; ay += v.y; az += v.z; aw += v.w;
  }
  ushort4 un = {f2bf_u16(ax * inv), f2bf_u16(ay * inv), f2bf_u16(az * inv), f2bf_u16(aw * inv)};
  reinterpret_cast<ushort4*>(out + (size_t)i * 2 * D + D)[c] = un;
}

// C[m][n] = sum_k A[m][k] * Bt[n][k]  (+bias, optional relu)
// A: [M][Kc] bf16 row-major, Bt: [N][Kc] bf16 row-major (pre-transposed).
// mfma_f32_16x16x32_bf16; A/B frag: row=lane&15, k=8*(lane>>4)+j;
// C/D frag: col=lane&15, row=(lane>>4)*4+r.
template <int BM, int BN, int WM, int WN, bool RELU>
__global__ void gemm_bf16(const unsigned short* __restrict__ A,
                          const unsigned short* __restrict__ Bt,
                          const float* __restrict__ bias,
                          float* __restrict__ C,
                          int M, int N, int Kc) {
  constexpr int BK = 32;
  constexpr int LDK = BK + 8;  // 80B row stride: b128 frag reads conflict-free (checked)
  constexpr int THREADS = WM * WN * 64;
  constexpr int MF = BM / (WM * 16);
  constexpr int NF = BN / (WN * 16);
  __shared__ __align__(16) unsigned short As[BM][LDK];
  __shared__ __align__(16) unsigned short Bs[BN][LDK];

  const int tid = threadIdx.x;
  const int wid = tid >> 6, lane = tid & 63;
  const int wm = wid / WN, wn = wid % WN;
  const size_t bm = (size_t)blockIdx.x * BM;
  const size_t bn = (size_t)blockIdx.y * BN;

  f32x4 acc[MF][NF];
#pragma unroll
  for (int mi = 0; mi < MF; ++mi)
#pragma unroll
    for (int ni = 0; ni < NF; ++ni)
      acc[mi][ni] = (f32x4){0.f, 0.f, 0.f, 0.f};

  const int arow = tid >> 2;           // THREADS/4 rows per pass
  const int apart = (tid & 3) * 8;     // 8 bf16 = 16B per thread
  const int klo = (lane >> 4) * 8;
  const int l15 = lane & 15;

  for (int kt = 0; kt < Kc; kt += BK) {
#pragma unroll
    for (int r = 0; r < BM; r += THREADS / 4) {
      s16x8 v = *reinterpret_cast<const s16x8*>(A + (bm + r + arow) * (size_t)Kc + kt + apart);
      *reinterpret_cast<s16x8*>(&As[r + arow][apart]) = v;
    }
#pragma unroll
    for (int r = 0; r < BN; r += THREADS / 4) {
      s16x8 v = *reinterpret_cast<const s16x8*>(Bt + (bn + r + arow) * (size_t)Kc + kt + apart);
      *reinterpret_cast<s16x8*>(&Bs[r + arow][apart]) = v;
    }
    __syncthreads();

    s16x8 af[MF], bfr[NF];
#pragma unroll
    for (int mi = 0; mi < MF; ++mi)
      af[mi] = *reinterpret_cast<const s16x8*>(&As[wm * MF * 16 + mi * 16 + l15][klo]);
#pragma unroll
    for (int ni = 0; ni < NF; ++ni)
      bfr[ni] = *reinterpret_cast<const s16x8*>(&Bs[wn * NF * 16 + ni * 16 + l15][klo]);
#pragma unroll
    for (int mi = 0; mi < MF; ++mi)
#pragma unroll
      for (int ni = 0; ni < NF; ++ni)
        acc[mi][ni] = __builtin_amdgcn_mfma_f32_16x16x32_bf16(af[mi], bfr[ni], acc[mi][ni], 0, 0, 0);
    __syncthreads();
  }

  const int rif = (lane >> 4) * 4;
#pragma unroll
  for (int mi = 0; mi < MF; ++mi) {
    size_t r0 = bm + wm * MF * 16 + mi * 16 + rif;
#pragma unroll
    for (int ni = 0; ni < NF; ++ni) {
      int c = (int)bn + wn * NF * 16 + ni * 16 + l15;
      float bv = bias[c];
#pragma unroll
      for (int r = 0; r < 4; ++r) {
        float v = acc[mi][ni][r] + bv;
        if (RELU) v = fmaxf(v, 0.f);
        C[(r0 + r) * (size_t)N + c] = v;
      }
    }
  }
}

// Final layer fused: row = [h1[i] | mean_5 h1[nbr2[i]]], out = row @ [Ws2;Wn2] + b2
__global__ void out_fused(const float* __restrict__ h1, const int* __restrict__ nbr,
                          const float* __restrict__ Ws, const float* __restrict__ Wn,
                          const float* __restrict__ b, float* __restrict__ out) {
  const int i = blockIdx.x, t = threadIdx.x;  // 256 threads
  __shared__ float row[512];
  __shared__ float part[8][32];
  row[t] = h1[(size_t)i * 256 + t];
  float s = 0.f;
#pragma unroll
  for (int f = 0; f < 5; ++f) s += h1[(size_t)nbr[i * 5 + f] * 256 + t];
  row[256 + t] = s * 0.2f;
  __syncthreads();
  const int n = t & 31, seg = t >> 5;  // 8 segments x 64 k-elems
  float p = 0.f;
  if (n < 19) {
#pragma unroll
    for (int e = 0; e < 64; ++e) {
      const int k = seg * 64 + e;
      const float w = (k < 256) ? Ws[k * 19 + n] : Wn[(k - 256) * 19 + n];
      p += row[k] * w;
    }
  }
  part[seg][n] = p;
  __syncthreads();
  if (t < 19) {
    float sm = b[t];
#pragma unroll
    for (int g = 0; g < 8; ++g) sm += part[g][t];
    out[(size_t)i * 19 + t] = sm;
  }
}

extern "C" void kernel_launch(void* const* d_in, const int* in_sizes, int n_in,
                              void* d_out, int out_size, void* d_ws, size_t ws_size,
                              hipStream_t stream) {
  const float* x    = (const float*)d_in[0];
  const int*   nbr0 = (const int*)d_in[1];
  const int*   nbr1 = (const int*)d_in[2];
  const int*   nbr2 = (const int*)d_in[3];
  const float* Ws0  = (const float*)d_in[4];
  const float* Wn0  = (const float*)d_in[5];
  const float* b0   = (const float*)d_in[6];
  const float* Ws1  = (const float*)d_in[7];
  const float* Wn1  = (const float*)d_in[8];
  const float* b1   = (const float*)d_in[9];
  const float* Ws2  = (const float*)d_in[10];
  const float* Wn2  = (const float*)d_in[11];
  const float* b2   = (const float*)d_in[12];
  float* out = (float*)d_out;

  char* ws = (char*)d_ws;
  unsigned short* A0   = (unsigned short*)(ws);                 // 25600*2048*2 = 104857600
  unsigned short* Wt0  = (unsigned short*)(ws + 104857600);     // 256*2048*2   =   1048576
  float*          h0   = (float*)(ws + 105906176);              // 25600*256*4  =  26214400
  unsigned short* cat1 = (unsigned short*)(ws + 132120576);     // 2560*512*2   =   2621440
  unsigned short* Wt1  = (unsigned short*)(ws + 134742016);     // 256*512*2    =    262144
  float*          h1   = (float*)(ws + 135004160);              // 2560*256*4   =   2621440
  // total ws use: ~137.6 MB

  prep_wcat<<<(256 * 2048 + 255) / 256, 256, 0, stream>>>(Ws0, Wn0, Wt0, 1024, 256);
  prep_wcat<<<(256 * 512 + 255) / 256, 256, 0, stream>>>(Ws1, Wn1, Wt1, 256, 256);

  gather_cat<1024, 10><<<25600, 256, 0, stream>>>(x, nbr0, A0);
  // 64x256 tile, 4 waves (each owns 64 N-cols), grid 400 -> ~6 blocks/CU by LDS
  gemm_bf16<64, 256, 1, 4, true>
      <<<dim3(400, 1), 256, 0, stream>>>(A0, Wt0, b0, h0, 25600, 256, 2048);

  gather_cat<256, 10><<<2560, 64, 0, stream>>>(h0, nbr1, cat1);
  gemm_bf16<64, 128, 2, 2, true>
      <<<dim3(40, 2), 256, 0, stream>>>(cat1, Wt1, b1, h1, 2560, 256, 512);

  out_fused<<<512, 256, 0, stream>>>(h1, nbr2, Ws2, Wn2, b2, out);
}

// Round 4
// 307.439 us; speedup vs baseline: 1.8772x; 1.0104x over previous
//
#include <hip/hip_runtime.h>
#include <hip/hip_bf16.h>

// GraphSAGE 3-layer inference, MI355X.
// R4: m97-class GEMM (BK=64, global_load_lds dwordx4, XOR-swizzled LDS) for
// layers 0 and 1; gathers unchanged (BW-bound); preps merged into one launch.
//
// Pipeline (6 launches):
//   prep_wcat2         : Wt0,Wt1 = bf16([Wself;Wneigh]^T)
//   gather_cat<1024,10>: A0 = [bf16(x_self) | bf16(mean nbr0)]   (25600 x 2048)
//   gemm_gl            : h0 = relu(A0 @ Wt0^T + b0)              (25600 x 256 f32)
//   gather_cat<256,10> : cat1                                    (2560 x 512)
//   gemm_gl            : h1 = relu(cat1 @ Wt1^T + b1)            (2560 x 256 f32)
//   out_fused          : out = [h1|mean nbr2] @ [Ws2;Wn2] + b2   (512 x 19 f32)

typedef __attribute__((ext_vector_type(4))) float f32x4;
typedef __attribute__((ext_vector_type(8))) short s16x8;

__device__ __forceinline__ unsigned short f2bf_u16(float f) {
  // round-to-nearest-even f32 -> bf16 (finite inputs only)
  unsigned int u = __float_as_uint(f);
  u += 0x7fffu + ((u >> 16) & 1u);
  return (unsigned short)(u >> 16);
}

__device__ __forceinline__ void gload16(const void* g, void* l) {
  // global -> LDS DMA, 16B per lane. LDS dest = wave-uniform base + lane*16.
  __builtin_amdgcn_global_load_lds(
      (const __attribute__((address_space(1))) unsigned int*)g,
      (__attribute__((address_space(3))) unsigned int*)l, 16, 0, 0);
}

// Both weight preps in one launch.
// Wt0[n][k] (256x2048), Wt1[n][k] (256x512), k-major bf16, [Wself;Wneigh]^T.
__global__ void prep_wcat2(const float* __restrict__ Ws0, const float* __restrict__ Wn0,
                           unsigned short* __restrict__ Wt0,
                           const float* __restrict__ Ws1, const float* __restrict__ Wn1,
                           unsigned short* __restrict__ Wt1) {
  int idx = blockIdx.x * 256 + threadIdx.x;
  if (idx < 256 * 2048) {
    int n = idx >> 11, k = idx & 2047;
    float v = (k < 1024) ? Ws0[k * 256 + n] : Wn0[(k - 1024) * 256 + n];
    Wt0[idx] = f2bf_u16(v);
  } else {
    int i2 = idx - 256 * 2048;
    if (i2 < 256 * 512) {
      int n = i2 >> 9, k = i2 & 511;
      float v = (k < 256) ? Ws1[k * 256 + n] : Wn1[(k - 256) * 256 + n];
      Wt1[i2] = f2bf_u16(v);
    }
  }
}

// One block per dst node; blockDim.x == D/4 exactly.
// out row (2*D bf16) = [ self | mean over F sampled neighbors ]
template <int D, int F>
__global__ void gather_cat(const float* __restrict__ h,
                           const int* __restrict__ nbr,
                           unsigned short* __restrict__ out) {
  const int i = blockIdx.x;
  const int c = threadIdx.x;  // float4 slot
  int idx[F];
#pragma unroll
  for (int f = 0; f < F; ++f) idx[f] = nbr[(size_t)i * F + f];
  constexpr float inv = 1.0f / (float)F;

  float4 s = reinterpret_cast<const float4*>(h + (size_t)i * D)[c];
  ushort4 us = {f2bf_u16(s.x), f2bf_u16(s.y), f2bf_u16(s.z), f2bf_u16(s.w)};
  reinterpret_cast<ushort4*>(out + (size_t)i * 2 * D)[c] = us;

  float ax = 0.f, ay = 0.f, az = 0.f, aw = 0.f;
#pragma unroll
  for (int f = 0; f < F; ++f) {
    float4 v = reinterpret_cast<const float4*>(h + (size_t)idx[f] * D)[c];
    ax += v.x; ay += v.y; az += v.z; aw += v.w;
  }
  ushort4 un = {f2bf_u16(ax * inv), f2bf_u16(ay * inv), f2bf_u16(az * inv), f2bf_u16(aw * inv)};
  reinterpret_cast<ushort4*>(out + (size_t)i * 2 * D + D)[c] = un;
}

// m97-class GEMM: C[m][n] = act(sum_k A[m][k]*Bt[n][k] + bias[n]).
// Fixed: BM=64, BN=N=256, BK=64, 256 threads = 4 waves, wave tile 64x64
// (MF=4 x NF=4 fragments of 16x16). Staging via global_load_lds dwordx4
// into LINEAR LDS [row][64] bf16 (128B rows); bank conflicts killed by
// granule XOR-swizzle applied on BOTH the global source (gs) and the
// ds_read side (gr) — rule 21.
// MFMA 16x16x32_bf16; A/B frag: row=lane&15, k=8*(lane>>4)+j;
// C/D frag: col=lane&15, row=(lane>>4)*4+r.
template <bool RELU>
__global__ __launch_bounds__(256) void gemm_gl(
    const unsigned short* __restrict__ A,   // [M][Kc] bf16 row-major
    const unsigned short* __restrict__ Bt,  // [256][Kc] bf16 row-major
    const float* __restrict__ bias,         // [256]
    float* __restrict__ C,                  // [M][256] f32
    int Kc) {
  constexpr int BM = 64, BN = 256, BK = 64;
  __shared__ __align__(16) unsigned short As[BM * BK];  //  8 KB
  __shared__ __align__(16) unsigned short Bs[BN * BK];  // 32 KB

  const int tid = threadIdx.x;
  const int wid = tid >> 6, lane = tid & 63;
  const size_t bm = (size_t)blockIdx.x * BM;

  // staging: each wave writes 8 consecutive 128B rows per pass; lane L covers
  // row (L>>3), granule (L&7). Source granule pre-swizzled by row&7.
  const int srow = (wid << 3) + (lane >> 3);            // 0..31 per pass
  const int gs = (lane & 7) ^ ((lane >> 3) & 7);        // src granule (inverse swz)
  const unsigned short* gA = A + (bm + srow) * (size_t)Kc + gs * 8;
  const unsigned short* gB = Bt + (size_t)srow * Kc + gs * 8;
  unsigned short* lA = As + wid * 512;  // wave-uniform
  unsigned short* lB = Bs + wid * 512;

  f32x4 acc[4][4];
#pragma unroll
  for (int mi = 0; mi < 4; ++mi)
#pragma unroll
    for (int ni = 0; ni < 4; ++ni)
      acc[mi][ni] = (f32x4){0.f, 0.f, 0.f, 0.f};

  const int l15 = lane & 15, lq = lane >> 4, l7 = lane & 7;

  for (int kt = 0; kt < Kc; kt += BK) {
    // A: 2 passes x 32 rows; B: 8 passes x 32 rows
    gload16(gA + kt, lA);
    gload16(gA + 32 * (size_t)Kc + kt, lA + 2048);
#pragma unroll
    for (int p = 0; p < 8; ++p)
      gload16(gB + p * 32 * (size_t)Kc + kt, lB + p * 2048);
    __syncthreads();  // drains vmcnt(0) (compiler-inserted before barrier)

#pragma unroll
    for (int ks = 0; ks < 2; ++ks) {
      const int gr = ((ks << 2) + lq) ^ l7;  // swizzled granule for frag reads
      s16x8 af[4], bf_[4];
#pragma unroll
      for (int mi = 0; mi < 4; ++mi) {
        const int row = mi * 16 + l15;
        af[mi] = *reinterpret_cast<const s16x8*>(
            reinterpret_cast<const char*>(As) + row * 128 + gr * 16);
      }
#pragma unroll
      for (int ni = 0; ni < 4; ++ni) {
        const int row = wid * 64 + ni * 16 + l15;
        bf_[ni] = *reinterpret_cast<const s16x8*>(
            reinterpret_cast<const char*>(Bs) + row * 128 + gr * 16);
      }
#pragma unroll
      for (int mi = 0; mi < 4; ++mi)
#pragma unroll
        for (int ni = 0; ni < 4; ++ni)
          acc[mi][ni] = __builtin_amdgcn_mfma_f32_16x16x32_bf16(af[mi], bf_[ni], acc[mi][ni], 0, 0, 0);
    }
    __syncthreads();
  }

  // epilogue: bias (+relu), f32 store
#pragma unroll
  for (int mi = 0; mi < 4; ++mi) {
    const size_t r0 = bm + mi * 16 + lq * 4;
#pragma unroll
    for (int ni = 0; ni < 4; ++ni) {
      const int c = wid * 64 + ni * 16 + l15;
      const float bv = bias[c];
#pragma unroll
      for (int rr = 0; rr < 4; ++rr) {
        float v = acc[mi][ni][rr] + bv;
        if (RELU) v = fmaxf(v, 0.f);
        C[(r0 + rr) * (size_t)BN + c] = v;
      }
    }
  }
}

// Final layer fused: row = [h1[i] | mean_5 h1[nbr2[i]]], out = row @ [Ws2;Wn2] + b2
__global__ void out_fused(const float* __restrict__ h1, const int* __restrict__ nbr,
                          const float* __restrict__ Ws, const float* __restrict__ Wn,
                          const float* __restrict__ b, float* __restrict__ out) {
  const int i = blockIdx.x, t = threadIdx.x;  // 256 threads
  __shared__ float row[512];
  __shared__ float part[8][32];
  row[t] = h1[(size_t)i * 256 + t];
  float s = 0.f;
#pragma unroll
  for (int f = 0; f < 5; ++f) s += h1[(size_t)nbr[i * 5 + f] * 256 + t];
  row[256 + t] = s * 0.2f;
  __syncthreads();
  const int n = t & 31, seg = t >> 5;  // 8 segments x 64 k-elems
  float p = 0.f;
  if (n < 19) {
#pragma unroll
    for (int e = 0; e < 64; ++e) {
      const int k = seg * 64 + e;
      const float w = (k < 256) ? Ws[k * 19 + n] : Wn[(k - 256) * 19 + n];
      p += row[k] * w;
    }
  }
  part[seg][n] = p;
  __syncthreads();
  if (t < 19) {
    float sm = b[t];
#pragma unroll
    for (int g = 0; g < 8; ++g) sm += part[g][t];
    out[(size_t)i * 19 + t] = sm;
  }
}

extern "C" void kernel_launch(void* const* d_in, const int* in_sizes, int n_in,
                              void* d_out, int out_size, void* d_ws, size_t ws_size,
                              hipStream_t stream) {
  const float* x    = (const float*)d_in[0];
  const int*   nbr0 = (const int*)d_in[1];
  const int*   nbr1 = (const int*)d_in[2];
  const int*   nbr2 = (const int*)d_in[3];
  const float* Ws0  = (const float*)d_in[4];
  const float* Wn0  = (const float*)d_in[5];
  const float* b0   = (const float*)d_in[6];
  const float* Ws1  = (const float*)d_in[7];
  const float* Wn1  = (const float*)d_in[8];
  const float* b1   = (const float*)d_in[9];
  const float* Ws2  = (const float*)d_in[10];
  const float* Wn2  = (const float*)d_in[11];
  const float* b2   = (const float*)d_in[12];
  float* out = (float*)d_out;

  char* ws = (char*)d_ws;
  unsigned short* A0   = (unsigned short*)(ws);                 // 25600*2048*2 = 104857600
  unsigned short* Wt0  = (unsigned short*)(ws + 104857600);     // 256*2048*2   =   1048576
  float*          h0   = (float*)(ws + 105906176);              // 25600*256*4  =  26214400
  unsigned short* cat1 = (unsigned short*)(ws + 132120576);     // 2560*512*2   =   2621440
  unsigned short* Wt1  = (unsigned short*)(ws + 134742016);     // 256*512*2    =    262144
  float*          h1   = (float*)(ws + 135004160);              // 2560*256*4   =   2621440
  // total ws use: ~137.6 MB

  prep_wcat2<<<(256 * 2048 + 256 * 512 + 255) / 256, 256, 0, stream>>>(
      Ws0, Wn0, Wt0, Ws1, Wn1, Wt1);

  gather_cat<1024, 10><<<25600, 256, 0, stream>>>(x, nbr0, A0);
  gemm_gl<true><<<400, 256, 0, stream>>>(A0, Wt0, b0, h0, 2048);

  gather_cat<256, 10><<<2560, 64, 0, stream>>>(h0, nbr1, cat1);
  gemm_gl<true><<<40, 256, 0, stream>>>(cat1, Wt1, b1, h1, 512);

  out_fused<<<512, 256, 0, stream>>>(h1, nbr2, Ws2, Wn2, b2, out);
}

// Round 5
// 292.089 us; speedup vs baseline: 1.9758x; 1.0525x over previous
//
#include <hip/hip_runtime.h>
#include <hip/hip_bf16.h>

// GraphSAGE 3-layer inference, MI355X.
// R5: gather0 with 16B/lane nontemporal stores (preserve L3 for x); weight
// prep fused into gather0 grid tail; m97-class GEMM unchanged.
//
// Pipeline (5 launches):
//   gather0_prep       : A0 = [bf16(x_self)|bf16(mean nbr0)] + Wt0/Wt1 prep
//   gemm_gl            : h0 = relu(A0 @ Wt0^T + b0)              (25600 x 256 f32)
//   gather_cat<256,10> : cat1                                    (2560 x 512)
//   gemm_gl            : h1 = relu(cat1 @ Wt1^T + b1)            (2560 x 256 f32)
//   out_fused          : out = [h1|mean nbr2] @ [Ws2;Wn2] + b2   (512 x 19 f32)

typedef __attribute__((ext_vector_type(4))) float f32x4;
typedef __attribute__((ext_vector_type(8))) short s16x8;

__device__ __forceinline__ unsigned short f2bf_u16(float f) {
  // round-to-nearest-even f32 -> bf16 (finite inputs only)
  unsigned int u = __float_as_uint(f);
  u += 0x7fffu + ((u >> 16) & 1u);
  return (unsigned short)(u >> 16);
}

__device__ __forceinline__ s16x8 pack_bf16x8(const float4& a, const float4& b) {
  s16x8 w;
  w[0] = (short)f2bf_u16(a.x); w[1] = (short)f2bf_u16(a.y);
  w[2] = (short)f2bf_u16(a.z); w[3] = (short)f2bf_u16(a.w);
  w[4] = (short)f2bf_u16(b.x); w[5] = (short)f2bf_u16(b.y);
  w[6] = (short)f2bf_u16(b.z); w[7] = (short)f2bf_u16(b.w);
  return w;
}

__device__ __forceinline__ void gload16(const void* g, void* l) {
  // global -> LDS DMA, 16B per lane. LDS dest = wave-uniform base + lane*16.
  __builtin_amdgcn_global_load_lds(
      (const __attribute__((address_space(1))) unsigned int*)g,
      (__attribute__((address_space(3))) unsigned int*)l, 16, 0, 0);
}

// Layer-0 gather (+ fused weight prep in tail blocks).
// Blocks [0, NDST): one dst node each, 128 threads, 8 floats/thread.
//   A0 row = [bf16(x[i]) | bf16(mean_10 x[nbr[i]])], 16B nontemporal stores.
// Blocks [NDST, NDST+40): grid-stride weight prep for Wt0 (256x2048) and
//   Wt1 (256x512): Wt[n][k] = bf16([Wself;Wneigh]^T). Reads are transposed
//   (stride 1KB) but the W tables are ~1MB -> L2-absorbed.
__global__ __launch_bounds__(128) void gather0_prep(
    const float* __restrict__ x, const int* __restrict__ nbr,
    unsigned short* __restrict__ A0,
    const float* __restrict__ Ws0, const float* __restrict__ Wn0,
    unsigned short* __restrict__ Wt0,
    const float* __restrict__ Ws1, const float* __restrict__ Wn1,
    unsigned short* __restrict__ Wt1) {
  constexpr int NDST = 25600, D = 1024, F = 10;
  const int bid = blockIdx.x, t = threadIdx.x;

  if (bid < NDST) {
    const size_t i = bid;
    int idx[F];
#pragma unroll
    for (int f = 0; f < F; ++f) idx[f] = nbr[i * F + f];

    // self: floats [8t, 8t+8)
    const float4* ps = reinterpret_cast<const float4*>(x + i * D) + 2 * t;
    float4 s0 = ps[0], s1 = ps[1];
    __builtin_nontemporal_store(
        pack_bf16x8(s0, s1), reinterpret_cast<s16x8*>(A0 + i * 2 * D) + t);

    // neighbor mean
    float4 a0 = make_float4(0.f, 0.f, 0.f, 0.f);
    float4 a1 = make_float4(0.f, 0.f, 0.f, 0.f);
#pragma unroll
    for (int f = 0; f < F; ++f) {
      const float4* p = reinterpret_cast<const float4*>(x + (size_t)idx[f] * D) + 2 * t;
      float4 u0 = p[0], u1 = p[1];
      a0.x += u0.x; a0.y += u0.y; a0.z += u0.z; a0.w += u0.w;
      a1.x += u1.x; a1.y += u1.y; a1.z += u1.z; a1.w += u1.w;
    }
    constexpr float inv = 1.0f / (float)F;
    a0.x *= inv; a0.y *= inv; a0.z *= inv; a0.w *= inv;
    a1.x *= inv; a1.y *= inv; a1.z *= inv; a1.w *= inv;
    __builtin_nontemporal_store(
        pack_bf16x8(a0, a1), reinterpret_cast<s16x8*>(A0 + i * 2 * D + D) + t);
  } else {
    const int pt = (bid - NDST) * 128 + t;  // 0..5119
    for (int e = pt; e < 256 * 2048; e += 5120) {
      int n = e >> 11, k = e & 2047;
      float v = (k < 1024) ? Ws0[k * 256 + n] : Wn0[(k - 1024) * 256 + n];
      Wt0[e] = f2bf_u16(v);
    }
    for (int e = pt; e < 256 * 512; e += 5120) {
      int n = e >> 9, k = e & 511;
      float v = (k < 256) ? Ws1[k * 256 + n] : Wn1[(k - 256) * 256 + n];
      Wt1[e] = f2bf_u16(v);
    }
  }
}

// One block per dst node; blockDim.x == D/4 exactly.
// out row (2*D bf16) = [ self | mean over F sampled neighbors ]
template <int D, int F>
__global__ void gather_cat(const float* __restrict__ h,
                           const int* __restrict__ nbr,
                           unsigned short* __restrict__ out) {
  const int i = blockIdx.x;
  const int c = threadIdx.x;  // float4 slot
  int idx[F];
#pragma unroll
  for (int f = 0; f < F; ++f) idx[f] = nbr[(size_t)i * F + f];
  constexpr float inv = 1.0f / (float)F;

  float4 s = reinterpret_cast<const float4*>(h + (size_t)i * D)[c];
  ushort4 us = {f2bf_u16(s.x), f2bf_u16(s.y), f2bf_u16(s.z), f2bf_u16(s.w)};
  reinterpret_cast<ushort4*>(out + (size_t)i * 2 * D)[c] = us;

  float ax = 0.f, ay = 0.f, az = 0.f, aw = 0.f;
#pragma unroll
  for (int f = 0; f < F; ++f) {
    float4 v = reinterpret_cast<const float4*>(h + (size_t)idx[f] * D)[c];
    ax += v.x; ay += v.y; az += v.z; aw += v.w;
  }
  ushort4 un = {f2bf_u16(ax * inv), f2bf_u16(ay * inv), f2bf_u16(az * inv), f2bf_u16(aw * inv)};
  reinterpret_cast<ushort4*>(out + (size_t)i * 2 * D + D)[c] = un;
}

// m97-class GEMM: C[m][n] = act(sum_k A[m][k]*Bt[n][k] + bias[n]).
// Fixed: BM=64, BN=N=256, BK=64, 256 threads = 4 waves, wave tile 64x64.
// Staging via global_load_lds dwordx4 into LINEAR LDS [row][64] bf16;
// bank conflicts killed by granule XOR-swizzle applied on BOTH the global
// source (gs) and the ds_read side (gr) — rule 21.
// MFMA 16x16x32_bf16; A/B frag: row=lane&15, k=8*(lane>>4)+j;
// C/D frag: col=lane&15, row=(lane>>4)*4+r.
template <bool RELU>
__global__ __launch_bounds__(256) void gemm_gl(
    const unsigned short* __restrict__ A,   // [M][Kc] bf16 row-major
    const unsigned short* __restrict__ Bt,  // [256][Kc] bf16 row-major
    const float* __restrict__ bias,         // [256]
    float* __restrict__ C,                  // [M][256] f32
    int Kc) {
  constexpr int BM = 64, BN = 256, BK = 64;
  __shared__ __align__(16) unsigned short As[BM * BK];  //  8 KB
  __shared__ __align__(16) unsigned short Bs[BN * BK];  // 32 KB

  const int tid = threadIdx.x;
  const int wid = tid >> 6, lane = tid & 63;
  const size_t bm = (size_t)blockIdx.x * BM;

  const int srow = (wid << 3) + (lane >> 3);            // 0..31 per pass
  const int gs = (lane & 7) ^ ((lane >> 3) & 7);        // src granule (inverse swz)
  const unsigned short* gA = A + (bm + srow) * (size_t)Kc + gs * 8;
  const unsigned short* gB = Bt + (size_t)srow * Kc + gs * 8;
  unsigned short* lA = As + wid * 512;  // wave-uniform
  unsigned short* lB = Bs + wid * 512;

  f32x4 acc[4][4];
#pragma unroll
  for (int mi = 0; mi < 4; ++mi)
#pragma unroll
    for (int ni = 0; ni < 4; ++ni)
      acc[mi][ni] = (f32x4){0.f, 0.f, 0.f, 0.f};

  const int l15 = lane & 15, lq = lane >> 4, l7 = lane & 7;

  for (int kt = 0; kt < Kc; kt += BK) {
    gload16(gA + kt, lA);
    gload16(gA + 32 * (size_t)Kc + kt, lA + 2048);
#pragma unroll
    for (int p = 0; p < 8; ++p)
      gload16(gB + p * 32 * (size_t)Kc + kt, lB + p * 2048);
    __syncthreads();  // compiler drains vmcnt(0) before barrier

#pragma unroll
    for (int ks = 0; ks < 2; ++ks) {
      const int gr = ((ks << 2) + lq) ^ l7;  // swizzled granule for frag reads
      s16x8 af[4], bf_[4];
#pragma unroll
      for (int mi = 0; mi < 4; ++mi) {
        const int row = mi * 16 + l15;
        af[mi] = *reinterpret_cast<const s16x8*>(
            reinterpret_cast<const char*>(As) + row * 128 + gr * 16);
      }
#pragma unroll
      for (int ni = 0; ni < 4; ++ni) {
        const int row = wid * 64 + ni * 16 + l15;
        bf_[ni] = *reinterpret_cast<const s16x8*>(
            reinterpret_cast<const char*>(Bs) + row * 128 + gr * 16);
      }
#pragma unroll
      for (int mi = 0; mi < 4; ++mi)
#pragma unroll
        for (int ni = 0; ni < 4; ++ni)
          acc[mi][ni] = __builtin_amdgcn_mfma_f32_16x16x32_bf16(af[mi], bf_[ni], acc[mi][ni], 0, 0, 0);
    }
    __syncthreads();
  }

#pragma unroll
  for (int mi = 0; mi < 4; ++mi) {
    const size_t r0 = bm + mi * 16 + lq * 4;
#pragma unroll
    for (int ni = 0; ni < 4; ++ni) {
      const int c = wid * 64 + ni * 16 + l15;
      const float bv = bias[c];
#pragma unroll
      for (int rr = 0; rr < 4; ++rr) {
        float v = acc[mi][ni][rr] + bv;
        if (RELU) v = fmaxf(v, 0.f);
        C[(r0 + rr) * (size_t)BN + c] = v;
      }
    }
  }
}

// Final layer fused: row = [h1[i] | mean_5 h1[nbr2[i]]], out = row @ [Ws2;Wn2] + b2
__global__ void out_fused(const float* __restrict__ h1, const int* __restrict__ nbr,
                          const float* __restrict__ Ws, const float* __restrict__ Wn,
                          const float* __restrict__ b, float* __restrict__ out) {
  const int i = blockIdx.x, t = threadIdx.x;  // 256 threads
  __shared__ float row[512];
  __shared__ float part[8][32];
  row[t] = h1[(size_t)i * 256 + t];
  float s = 0.f;
#pragma unroll
  for (int f = 0; f < 5; ++f) s += h1[(size_t)nbr[i * 5 + f] * 256 + t];
  row[256 + t] = s * 0.2f;
  __syncthreads();
  const int n = t & 31, seg = t >> 5;  // 8 segments x 64 k-elems
  float p = 0.f;
  if (n < 19) {
#pragma unroll
    for (int e = 0; e < 64; ++e) {
      const int k = seg * 64 + e;
      const float w = (k < 256) ? Ws[k * 19 + n] : Wn[(k - 256) * 19 + n];
      p += row[k] * w;
    }
  }
  part[seg][n] = p;
  __syncthreads();
  if (t < 19) {
    float sm = b[t];
#pragma unroll
    for (int g = 0; g < 8; ++g) sm += part[g][t];
    out[(size_t)i * 19 + t] = sm;
  }
}

extern "C" void kernel_launch(void* const* d_in, const int* in_sizes, int n_in,
                              void* d_out, int out_size, void* d_ws, size_t ws_size,
                              hipStream_t stream) {
  const float* x    = (const float*)d_in[0];
  const int*   nbr0 = (const int*)d_in[1];
  const int*   nbr1 = (const int*)d_in[2];
  const int*   nbr2 = (const int*)d_in[3];
  const float* Ws0  = (const float*)d_in[4];
  const float* Wn0  = (const float*)d_in[5];
  const float* b0   = (const float*)d_in[6];
  const float* Ws1  = (const float*)d_in[7];
  const float* Wn1  = (const float*)d_in[8];
  const float* b1   = (const float*)d_in[9];
  const float* Ws2  = (const float*)d_in[10];
  const float* Wn2  = (const float*)d_in[11];
  const float* b2   = (const float*)d_in[12];
  float* out = (float*)d_out;

  char* ws = (char*)d_ws;
  unsigned short* A0   = (unsigned short*)(ws);                 // 25600*2048*2 = 104857600
  unsigned short* Wt0  = (unsigned short*)(ws + 104857600);     // 256*2048*2   =   1048576
  float*          h0   = (float*)(ws + 105906176);              // 25600*256*4  =  26214400
  unsigned short* cat1 = (unsigned short*)(ws + 132120576);     // 2560*512*2   =   2621440
  unsigned short* Wt1  = (unsigned short*)(ws + 134742016);     // 256*512*2    =    262144
  float*          h1   = (float*)(ws + 135004160);              // 2560*256*4   =   2621440
  // total ws use: ~137.6 MB

  gather0_prep<<<25600 + 40, 128, 0, stream>>>(x, nbr0, A0, Ws0, Wn0, Wt0, Ws1, Wn1, Wt1);
  gemm_gl<true><<<400, 256, 0, stream>>>(A0, Wt0, b0, h0, 2048);

  gather_cat<256, 10><<<2560, 64, 0, stream>>>(h0, nbr1, cat1);
  gemm_gl<true><<<40, 256, 0, stream>>>(cat1, Wt1, b1, h1, 512);

  out_fused<<<512, 256, 0, stream>>>(h1, nbr2, Ws2, Wn2, b2, out);
}